// Round 4
// baseline (1091.210 us; speedup 1.0000x reference)
//
#include <hip/hip_runtime.h>
#include <cmath>

#define NLEV 16
#define HASH_START 12               // levels >= 12 use spatial hash ((r+1)^2 > 2^19)
#define HMASK ((1u << 19) - 1u)     // hash level size is exactly 2^19
#define HASH_PRIME 2654435761u

struct LvlC {
  float scale[NLEV];
  unsigned stride[NLEV];   // res + 1
  unsigned offset[NLEV];   // cumulative param offset (multiple of 8)
};

// Process levels [L0,L1) for 4 points, accumulate in VGPRs, store one full
// 64B line per point (16 floats = 8 levels x 2ch). Hash clusters issue 16
// independent gathers per wave-iteration before any consume -> per-wave MLP.
template <int L0, int L1>
__device__ __forceinline__ void process_half(
    const float u[4][3], const float2* __restrict__ txy,
    const float2* __restrict__ txz, const float2* __restrict__ tyz,
    const LvlC& lc, float* __restrict__ outrow0)
{
  float acc[4][2 * (L1 - L0)];
#pragma unroll
  for (int k = 0; k < 4; ++k)
#pragma unroll
    for (int j = 0; j < 2 * (L1 - L0); ++j) acc[k][j] = 0.0f;

#pragma unroll
  for (int l = L0; l < L1; ++l) {
    const float sc = lc.scale[l];
    const unsigned o = lc.offset[l];
    const unsigned s = lc.stride[l];
#pragma unroll
    for (int p = 0; p < 3; ++p) {
      const float2* __restrict__ tab = (p == 0) ? txy : ((p == 1) ? txz : tyz);
      const int A = (p == 2) ? 1 : 0;        // COO_COMBS = (0,1),(0,2),(1,2)
      const int B = (p == 0) ? 1 : 2;
      if (l >= HASH_START) {
        float rx[4], ry[4];
        float2 f[4][4];
#pragma unroll
        for (int k = 0; k < 4; ++k) {
          float px = u[k][A] * sc + 0.5f;
          float py = u[k][B] * sc + 0.5f;
          float fx = floorf(px), fy = floorf(py);
          rx[k] = px - fx; ry[k] = py - fy;
          unsigned x0 = (unsigned)fx, y0 = (unsigned)fy;
          unsigned hy0 = y0 * HASH_PRIME;
          unsigned hy1 = hy0 + HASH_PRIME;   // (y0+1)*prime mod 2^32
          f[k][0] = tab[o + ((x0 ^ hy0) & HMASK)];
          f[k][1] = tab[o + (((x0 + 1u) ^ hy0) & HMASK)];
          f[k][2] = tab[o + ((x0 ^ hy1) & HMASK)];
          f[k][3] = tab[o + (((x0 + 1u) ^ hy1) & HMASK)];
        }
#pragma unroll
        for (int k = 0; k < 4; ++k) {
          float w00 = (1.f - rx[k]) * (1.f - ry[k]), w10 = rx[k] * (1.f - ry[k]);
          float w01 = (1.f - rx[k]) * ry[k],          w11 = rx[k] * ry[k];
          acc[k][2 * (l - L0) + 0] += w00 * f[k][0].x + w10 * f[k][1].x +
                                      w01 * f[k][2].x + w11 * f[k][3].x;
          acc[k][2 * (l - L0) + 1] += w00 * f[k][0].y + w10 * f[k][1].y +
                                      w01 * f[k][2].y + w11 * f[k][3].y;
        }
      } else {
        float rx[4], ry[4];
        float4 r[4][2];
#pragma unroll
        for (int k = 0; k < 4; ++k) {
          float px = u[k][A] * sc + 0.5f;
          float py = u[k][B] * sc + 0.5f;
          float fx = floorf(px), fy = floorf(py);
          rx[k] = px - fx; ry[k] = py - fy;
          unsigned x0 = (unsigned)fx, y0 = (unsigned)fy;
          unsigned i00 = x0 + y0 * s;
          r[k][0] = *reinterpret_cast<const float4*>(tab + o + i00);      // f00,f10
          r[k][1] = *reinterpret_cast<const float4*>(tab + o + i00 + s);  // f01,f11
        }
#pragma unroll
        for (int k = 0; k < 4; ++k) {
          float w00 = (1.f - rx[k]) * (1.f - ry[k]), w10 = rx[k] * (1.f - ry[k]);
          float w01 = (1.f - rx[k]) * ry[k],          w11 = rx[k] * ry[k];
          acc[k][2 * (l - L0) + 0] += w00 * r[k][0].x + w10 * r[k][0].z +
                                      w01 * r[k][1].x + w11 * r[k][1].z;
          acc[k][2 * (l - L0) + 1] += w00 * r[k][0].y + w10 * r[k][0].w +
                                      w01 * r[k][1].y + w11 * r[k][1].w;
        }
      }
    }
  }

  // point 4t+k's output row: 32 floats; this half covers floats [2*L0, 2*L1)
  // = one full 64B line -> no partial-line write inflation.
#pragma unroll
  for (int k = 0; k < 4; ++k) {
    float4* o4 = reinterpret_cast<float4*>(outrow0 + (size_t)k * (2 * NLEV) + 2 * L0);
#pragma unroll
    for (int j = 0; j < 4; ++j)
      o4[j] = make_float4(acc[k][4 * j + 0], acc[k][4 * j + 1],
                          acc[k][4 * j + 2], acc[k][4 * j + 3]);
  }
}

__global__ __launch_bounds__(256, 4) void hgp_kernel(
    const float* __restrict__ pts,
    const float2* __restrict__ txy,
    const float2* __restrict__ txz,
    const float2* __restrict__ tyz,
    float* __restrict__ out,
    LvlC lc, int nquads)
{
  int t = blockIdx.x * 256 + threadIdx.x;
  if (t >= nquads) return;

  // 4 contiguous points: 12 floats = 3 aligned float4 loads (48B | 16)
  const float4* p4 = reinterpret_cast<const float4*>(pts) + 3 * (size_t)t;
  float4 c0 = p4[0], c1 = p4[1], c2 = p4[2];

  // normalize: u = (x+1)*0.5  (GridEncoder.forward)
  float u[4][3];
  u[0][0] = (c0.x + 1.f) * 0.5f; u[0][1] = (c0.y + 1.f) * 0.5f; u[0][2] = (c0.z + 1.f) * 0.5f;
  u[1][0] = (c0.w + 1.f) * 0.5f; u[1][1] = (c1.x + 1.f) * 0.5f; u[1][2] = (c1.y + 1.f) * 0.5f;
  u[2][0] = (c1.z + 1.f) * 0.5f; u[2][1] = (c1.w + 1.f) * 0.5f; u[2][2] = (c2.x + 1.f) * 0.5f;
  u[3][0] = (c2.y + 1.f) * 0.5f; u[3][1] = (c2.z + 1.f) * 0.5f; u[3][2] = (c2.w + 1.f) * 0.5f;

  float* outrow0 = out + (size_t)(4 * t) * (2 * NLEV);

  process_half<0, 8>(u, txy, txz, tyz, lc, outrow0);   // small dense levels (L1/L2-hit)
  process_half<8, 16>(u, txy, txz, tyz, lc, outrow0);  // big dense + hash levels
}

static void compute_levels(LvlC* lc)
{
  // Mirrors the Python _level_constants() with identical double-precision ops.
  const double pls = std::pow(2.0, std::log2(2048.0 / 16.0) / 15.0);
  unsigned long long off = 0;
  for (int l = 0; l < NLEV; ++l) {
    double s = 16.0 * std::pow(pls, (double)l) - 1.0;
    lc->scale[l] = (float)s;
    long long r = (long long)std::ceil(s) + 1;
    long long dense = (r + 1) * (r + 1);
    long long sz = dense < (1LL << 19) ? dense : (1LL << 19);
    sz = ((sz + 7) / 8) * 8;
    lc->stride[l] = (unsigned)(r + 1);
    lc->offset[l] = (unsigned)off;
    off += (unsigned long long)sz;
  }
}

extern "C" void kernel_launch(void* const* d_in, const int* in_sizes, int n_in,
                              void* d_out, int out_size, void* d_ws, size_t ws_size,
                              hipStream_t stream) {
  const float*  pts = (const float*)d_in[0];
  const float2* txy = (const float2*)d_in[1];
  const float2* txz = (const float2*)d_in[2];
  const float2* tyz = (const float2*)d_in[3];
  float* out = (float*)d_out;

  int n = in_sizes[0] / 3;  // 1048576 points
  int nquads = n / 4;

  LvlC lc;
  compute_levels(&lc);

  int block = 256;
  int grid = (nquads + block - 1) / block;
  hgp_kernel<<<grid, block, 0, stream>>>(pts, txy, txz, tyz, out, lc, nquads);
}

// Round 6
// 524.968 us; speedup vs baseline: 2.0786x; 2.0786x over previous
//
#include <hip/hip_runtime.h>
#include <hip/hip_fp16.h>
#include <cmath>

#define NLEV 16
#define HASH_START 12               // levels >= 12 use spatial hash ((r+1)^2 > 2^19)
#define HMASK ((1u << 19) - 1u)     // hash level size is exactly 2^19
#define HASH_PRIME 2654435761u

typedef float f4 __attribute__((ext_vector_type(4)));  // native vec for nontemporal stores

struct LvlC {
  float scale[NLEV];
  unsigned stride[NLEV];   // res + 1
  unsigned offset[NLEV];   // cumulative param offset (multiple of 8)
};

__device__ __forceinline__ float2 h2f(unsigned u) {
  return __half22float2(__builtin_bit_cast(__half2, u));
}
__device__ __forceinline__ void nt_store4(float* p, float a, float b, float c, float d) {
  f4 v = {a, b, c, d};
  __builtin_nontemporal_store(v, reinterpret_cast<f4*>(p));
}

// ---- pass 0: fp32 tables -> fp16 copies in ws (halves every footprint) ----
__global__ __launch_bounds__(256) void k_convert(
    const float2* __restrict__ t0, const float2* __restrict__ t1,
    const float2* __restrict__ t2, unsigned* __restrict__ dst, unsigned total)
{
  unsigned g = blockIdx.x * 256 + threadIdx.x;
  unsigned stp = gridDim.x * 256;
  unsigned tot3 = 3u * total;
  for (unsigned e = g; e < tot3; e += stp) {
    const float2* src; unsigned i = e;
    if (i < total)            { src = t0; }
    else if (i < 2u * total)  { src = t1; i -= total; }
    else                      { src = t2; i -= 2u * total; }
    float2 v = src[i];
    __half2 h = __floats2half2_rn(v.x, v.y);
    __builtin_nontemporal_store(__builtin_bit_cast(unsigned, h), dst + e);
  }
}

// ---- pass 1: levels 0-9 (small dense tables, L1/L2-hot) -> out[0..20) ----
__global__ __launch_bounds__(256) void k_coarse(
    const float* __restrict__ pts, const unsigned* __restrict__ tab,
    float* __restrict__ out, LvlC lc, unsigned total, int n)
{
  int i = blockIdx.x * 256 + threadIdx.x;
  if (i >= n) return;
  float u0 = (pts[3 * i + 0] + 1.f) * .5f;
  float u1 = (pts[3 * i + 1] + 1.f) * .5f;
  float u2 = (pts[3 * i + 2] + 1.f) * .5f;
  const float ua[3] = {u0, u0, u1}, ub[3] = {u1, u2, u2};
  float res[20];
#pragma unroll
  for (int l = 0; l < 10; ++l) {
    float s0 = 0.f, s1 = 0.f;
    const float sc = lc.scale[l];
    const unsigned o = lc.offset[l], s = lc.stride[l];
#pragma unroll
    for (int p = 0; p < 3; ++p) {
      const unsigned* t = tab + (size_t)p * total + o;
      float px = ua[p] * sc + .5f, py = ub[p] * sc + .5f;
      float fx = floorf(px), fy = floorf(py);
      float rx = px - fx, ry = py - fy;
      unsigned i00 = (unsigned)fx + (unsigned)fy * s;
      uint2 r0 = *reinterpret_cast<const uint2*>(t + i00);      // entries x0,x0+1
      uint2 r1 = *reinterpret_cast<const uint2*>(t + i00 + s);
      float2 f00 = h2f(r0.x), f10 = h2f(r0.y), f01 = h2f(r1.x), f11 = h2f(r1.y);
      float w00 = (1.f - rx) * (1.f - ry), w10 = rx * (1.f - ry);
      float w01 = (1.f - rx) * ry,          w11 = rx * ry;
      s0 += w00 * f00.x + w10 * f10.x + w01 * f01.x + w11 * f11.x;
      s1 += w00 * f00.y + w10 * f10.y + w01 * f01.y + w11 * f11.y;
    }
    res[2 * l] = s0; res[2 * l + 1] = s1;
  }
  float* orow = out + (size_t)i * 32;
#pragma unroll
  for (int j = 0; j < 5; ++j)
    nt_store4(orow + 4 * j, res[4 * j], res[4 * j + 1], res[4 * j + 2], res[4 * j + 3]);
}

// ---- dense level 10/11: 3 planes -> half2 slice (L2-resident table) ----
__global__ __launch_bounds__(256) void k_dense_lvl(
    const float* __restrict__ pts, const unsigned* __restrict__ tab,
    unsigned* __restrict__ slice, float sc, unsigned s, unsigned o,
    unsigned total, int n)
{
  int i = blockIdx.x * 256 + threadIdx.x;
  if (i >= n) return;
  float u0 = (pts[3 * i + 0] + 1.f) * .5f;
  float u1 = (pts[3 * i + 1] + 1.f) * .5f;
  float u2 = (pts[3 * i + 2] + 1.f) * .5f;
  const float ua[3] = {u0, u0, u1}, ub[3] = {u1, u2, u2};
  float s0 = 0.f, s1 = 0.f;
#pragma unroll
  for (int p = 0; p < 3; ++p) {
    const unsigned* t = tab + (size_t)p * total + o;
    float px = ua[p] * sc + .5f, py = ub[p] * sc + .5f;
    float fx = floorf(px), fy = floorf(py);
    float rx = px - fx, ry = py - fy;
    unsigned i00 = (unsigned)fx + (unsigned)fy * s;
    uint2 r0 = *reinterpret_cast<const uint2*>(t + i00);
    uint2 r1 = *reinterpret_cast<const uint2*>(t + i00 + s);
    float2 f00 = h2f(r0.x), f10 = h2f(r0.y), f01 = h2f(r1.x), f11 = h2f(r1.y);
    float w00 = (1.f - rx) * (1.f - ry), w10 = rx * (1.f - ry);
    float w01 = (1.f - rx) * ry,          w11 = rx * ry;
    s0 += w00 * f00.x + w10 * f10.x + w01 * f01.x + w11 * f11.x;
    s1 += w00 * f00.y + w10 * f10.y + w01 * f01.y + w11 * f11.y;
  }
  __builtin_nontemporal_store(
      __builtin_bit_cast(unsigned, __floats2half2_rn(s0, s1)), slice + i);
}

// ---- hash level, planes 0+1 (2x 2MB tables, both L2-resident) ----
__global__ __launch_bounds__(256) void k_hash01(
    const float* __restrict__ pts, const unsigned* __restrict__ tab,
    unsigned* __restrict__ slice, float sc, unsigned o, unsigned total, int n)
{
  int i = blockIdx.x * 256 + threadIdx.x;
  if (i >= n) return;
  float u0 = (pts[3 * i + 0] + 1.f) * .5f;
  float u1 = (pts[3 * i + 1] + 1.f) * .5f;
  float u2 = (pts[3 * i + 2] + 1.f) * .5f;
  const float ua[2] = {u0, u0}, ub[2] = {u1, u2};  // planes (0,1),(0,2)
  float s0 = 0.f, s1 = 0.f;
#pragma unroll
  for (int p = 0; p < 2; ++p) {
    const unsigned* t = tab + (size_t)p * total + o;
    float px = ua[p] * sc + .5f, py = ub[p] * sc + .5f;
    float fx = floorf(px), fy = floorf(py);
    float rx = px - fx, ry = py - fy;
    unsigned x0 = (unsigned)fx, y0 = (unsigned)fy;
    unsigned hy0 = y0 * HASH_PRIME, hy1 = hy0 + HASH_PRIME;
    unsigned g0 = t[(x0 ^ hy0) & HMASK];
    unsigned g1 = t[((x0 + 1u) ^ hy0) & HMASK];
    unsigned g2 = t[(x0 ^ hy1) & HMASK];
    unsigned g3 = t[((x0 + 1u) ^ hy1) & HMASK];
    float2 f00 = h2f(g0), f10 = h2f(g1), f01 = h2f(g2), f11 = h2f(g3);
    float w00 = (1.f - rx) * (1.f - ry), w10 = rx * (1.f - ry);
    float w01 = (1.f - rx) * ry,          w11 = rx * ry;
    s0 += w00 * f00.x + w10 * f10.x + w01 * f01.x + w11 * f11.x;
    s1 += w00 * f00.y + w10 * f10.y + w01 * f01.y + w11 * f11.y;
  }
  __builtin_nontemporal_store(
      __builtin_bit_cast(unsigned, __floats2half2_rn(s0, s1)), slice + i);
}

// ---- hash level, plane 2 (yz), accumulates into slice ----
__global__ __launch_bounds__(256) void k_hash2(
    const float* __restrict__ pts, const unsigned* __restrict__ tab,
    unsigned* __restrict__ slice, float sc, unsigned o, unsigned total, int n)
{
  int i = blockIdx.x * 256 + threadIdx.x;
  if (i >= n) return;
  float u1 = (pts[3 * i + 1] + 1.f) * .5f;
  float u2 = (pts[3 * i + 2] + 1.f) * .5f;
  const unsigned* t = tab + (size_t)2 * total + o;
  float px = u1 * sc + .5f, py = u2 * sc + .5f;
  float fx = floorf(px), fy = floorf(py);
  float rx = px - fx, ry = py - fy;
  unsigned x0 = (unsigned)fx, y0 = (unsigned)fy;
  unsigned hy0 = y0 * HASH_PRIME, hy1 = hy0 + HASH_PRIME;
  unsigned g0 = t[(x0 ^ hy0) & HMASK];
  unsigned g1 = t[((x0 + 1u) ^ hy0) & HMASK];
  unsigned g2 = t[(x0 ^ hy1) & HMASK];
  unsigned g3 = t[((x0 + 1u) ^ hy1) & HMASK];
  float2 prev = h2f(slice[i]);
  float2 f00 = h2f(g0), f10 = h2f(g1), f01 = h2f(g2), f11 = h2f(g3);
  float w00 = (1.f - rx) * (1.f - ry), w10 = rx * (1.f - ry);
  float w01 = (1.f - rx) * ry,          w11 = rx * ry;
  float s0 = prev.x + w00 * f00.x + w10 * f10.x + w01 * f01.x + w11 * f11.x;
  float s1 = prev.y + w00 * f00.y + w10 * f10.y + w01 * f01.y + w11 * f11.y;
  __builtin_nontemporal_store(
      __builtin_bit_cast(unsigned, __floats2half2_rn(s0, s1)), slice + i);
}

// ---- merge 6 slices (levels 10-15) -> out[20..32) ----
__global__ __launch_bounds__(256) void k_merge(
    const unsigned* __restrict__ slices, float* __restrict__ out, int n)
{
  int i = blockIdx.x * 256 + threadIdx.x;
  if (i >= n) return;
  float v[12];
#pragma unroll
  for (int j = 0; j < 6; ++j) {
    float2 f = h2f(slices[(size_t)j * n + i]);
    v[2 * j] = f.x; v[2 * j + 1] = f.y;
  }
  float* orow = out + (size_t)i * 32 + 20;
#pragma unroll
  for (int j = 0; j < 3; ++j)
    nt_store4(orow + 4 * j, v[4 * j], v[4 * j + 1], v[4 * j + 2], v[4 * j + 3]);
}

// ---- fallback (ws too small): R2-style monolithic fp32 kernel ----
__global__ __launch_bounds__(256) void k_fallback(
    const float* __restrict__ pts, const float2* __restrict__ txy,
    const float2* __restrict__ txz, const float2* __restrict__ tyz,
    float* __restrict__ out, LvlC lc, int n)
{
  int i = blockIdx.x * 256 + threadIdx.x;
  if (i >= n) return;
  float u0 = (pts[3 * i + 0] + 1.f) * .5f;
  float u1 = (pts[3 * i + 1] + 1.f) * .5f;
  float u2 = (pts[3 * i + 2] + 1.f) * .5f;
  const float ua[3] = {u0, u0, u1}, ub[3] = {u1, u2, u2};
  const float2* tabs[3] = {txy, txz, tyz};
  float acc[32];
#pragma unroll
  for (int j = 0; j < 32; ++j) acc[j] = 0.f;
#pragma unroll
  for (int l = 0; l < NLEV; ++l) {
    const float sc = lc.scale[l];
    const unsigned o = lc.offset[l], s = lc.stride[l];
#pragma unroll
    for (int p = 0; p < 3; ++p) {
      const float2* t = tabs[p];
      float px = ua[p] * sc + .5f, py = ub[p] * sc + .5f;
      float fx = floorf(px), fy = floorf(py);
      float rx = px - fx, ry = py - fy;
      unsigned x0 = (unsigned)fx, y0 = (unsigned)fy;
      float w00 = (1.f - rx) * (1.f - ry), w10 = rx * (1.f - ry);
      float w01 = (1.f - rx) * ry,          w11 = rx * ry;
      float2 f00, f10, f01, f11;
      if (l >= HASH_START) {
        unsigned hy0 = y0 * HASH_PRIME, hy1 = hy0 + HASH_PRIME;
        f00 = t[o + ((x0 ^ hy0) & HMASK)];
        f10 = t[o + (((x0 + 1u) ^ hy0) & HMASK)];
        f01 = t[o + ((x0 ^ hy1) & HMASK)];
        f11 = t[o + (((x0 + 1u) ^ hy1) & HMASK)];
      } else {
        unsigned i00 = x0 + y0 * s;
        float4 r0 = *reinterpret_cast<const float4*>(t + o + i00);
        float4 r1 = *reinterpret_cast<const float4*>(t + o + i00 + s);
        f00 = make_float2(r0.x, r0.y); f10 = make_float2(r0.z, r0.w);
        f01 = make_float2(r1.x, r1.y); f11 = make_float2(r1.z, r1.w);
      }
      acc[2 * l + 0] += w00 * f00.x + w10 * f10.x + w01 * f01.x + w11 * f11.x;
      acc[2 * l + 1] += w00 * f00.y + w10 * f10.y + w01 * f01.y + w11 * f11.y;
    }
  }
  float* orow = out + (size_t)i * 32;
#pragma unroll
  for (int j = 0; j < 8; ++j)
    nt_store4(orow + 4 * j, acc[4 * j], acc[4 * j + 1], acc[4 * j + 2], acc[4 * j + 3]);
}

static unsigned compute_levels(LvlC* lc)
{
  // Mirrors Python _level_constants() with identical double-precision ops.
  const double pls = std::pow(2.0, std::log2(2048.0 / 16.0) / 15.0);
  unsigned long long off = 0;
  for (int l = 0; l < NLEV; ++l) {
    double s = 16.0 * std::pow(pls, (double)l) - 1.0;
    lc->scale[l] = (float)s;
    long long r = (long long)std::ceil(s) + 1;
    long long dense = (r + 1) * (r + 1);
    long long sz = dense < (1LL << 19) ? dense : (1LL << 19);
    sz = ((sz + 7) / 8) * 8;
    lc->stride[l] = (unsigned)(r + 1);
    lc->offset[l] = (unsigned)off;
    off += (unsigned long long)sz;
  }
  return (unsigned)off;
}

extern "C" void kernel_launch(void* const* d_in, const int* in_sizes, int n_in,
                              void* d_out, int out_size, void* d_ws, size_t ws_size,
                              hipStream_t stream) {
  const float*  pts = (const float*)d_in[0];
  const float2* txy = (const float2*)d_in[1];
  const float2* txz = (const float2*)d_in[2];
  const float2* tyz = (const float2*)d_in[3];
  float* out = (float*)d_out;
  int n = in_sizes[0] / 3;  // 1048576 points

  LvlC lc;
  unsigned total = compute_levels(&lc);

  size_t tab_bytes = (size_t)3 * total * 4;
  size_t tab_al = (tab_bytes + 255) & ~(size_t)255;
  size_t need = tab_al + (size_t)6 * n * 4;

  int block = 256;
  int grid = (n + block - 1) / block;

  if (ws_size < need) {  // safety fallback: monolithic fp32
    k_fallback<<<grid, block, 0, stream>>>(pts, txy, txz, tyz, out, lc, n);
    return;
  }

  unsigned* tab16 = (unsigned*)d_ws;
  unsigned* slices = (unsigned*)((char*)d_ws + tab_al);

  k_convert<<<2048, 256, 0, stream>>>(txy, txz, tyz, tab16, total);
  k_coarse<<<grid, block, 0, stream>>>(pts, tab16, out, lc, total, n);

  for (int l = 10; l < 12; ++l)
    k_dense_lvl<<<grid, block, 0, stream>>>(pts, tab16, slices + (size_t)(l - 10) * n,
                                            lc.scale[l], lc.stride[l], lc.offset[l], total, n);
  for (int l = HASH_START; l < NLEV; ++l) {
    unsigned* sl = slices + (size_t)(l - 10) * n;
    k_hash01<<<grid, block, 0, stream>>>(pts, tab16, sl, lc.scale[l], lc.offset[l], total, n);
    k_hash2 <<<grid, block, 0, stream>>>(pts, tab16, sl, lc.scale[l], lc.offset[l], total, n);
  }
  k_merge<<<grid, block, 0, stream>>>(slices, out, n);
}

// Round 7
// 397.299 us; speedup vs baseline: 2.7466x; 1.3213x over previous
//
#include <hip/hip_runtime.h>
#include <hip/hip_fp16.h>
#include <cmath>

#define NLEV 16
#define HASH_START 12               // levels >= 12 use spatial hash ((r+1)^2 > 2^19)
#define HMASK ((1u << 19) - 1u)     // hash level size is exactly 2^19
#define HASH_PRIME 2654435761u
#define LDS_WORDS 14160             // offset[6]: total entries of levels 0-5 (guarded on host)

typedef float    f4 __attribute__((ext_vector_type(4)));
typedef unsigned u4 __attribute__((ext_vector_type(4)));

struct LvlC {
  float scale[NLEV];
  unsigned stride[NLEV];   // res + 1
  unsigned offset[NLEV];   // cumulative param offset (multiple of 8)
};

__device__ __forceinline__ float2 h2f(unsigned u) {
  return __half22float2(__builtin_bit_cast(__half2, u));
}
__device__ __forceinline__ void nt_store4(float* p, float a, float b, float c, float d) {
  f4 v = {a, b, c, d};
  __builtin_nontemporal_store(v, reinterpret_cast<f4*>(p));
}

// ---- pass 0: fp32 tables -> fp16 copies in ws ----
__global__ __launch_bounds__(256) void k_convert(
    const float2* __restrict__ t0, const float2* __restrict__ t1,
    const float2* __restrict__ t2, unsigned* __restrict__ dst, unsigned total)
{
  unsigned g = blockIdx.x * 256 + threadIdx.x;
  unsigned stp = gridDim.x * 256;
  unsigned tot3 = 3u * total;
  for (unsigned e = g; e < tot3; e += stp) {
    const float2* src; unsigned i = e;
    if (i < total)            { src = t0; }
    else if (i < 2u * total)  { src = t1; i -= total; }
    else                      { src = t2; i -= 2u * total; }
    float2 v = src[i];
    __half2 h = __floats2half2_rn(v.x, v.y);
    __builtin_nontemporal_store(__builtin_bit_cast(unsigned, h), dst + e);
  }
}

// ---- dense levels 10,11: 2 pts/thread, 24 gathers in flight -> 2 slices ----
__global__ __launch_bounds__(256) void k_dense1011(
    const float* __restrict__ pts, const unsigned* __restrict__ tab,
    unsigned* __restrict__ s10, unsigned* __restrict__ s11,
    LvlC lc, unsigned total, int half)
{
  int t = blockIdx.x * 256 + threadIdx.x;
  if (t >= half) return;
  const int idx[2] = {t, t + half};

  float ua[2][3], ub[2][3];
#pragma unroll
  for (int k = 0; k < 2; ++k) {
    float u0 = (pts[3 * idx[k] + 0] + 1.f) * .5f;
    float u1 = (pts[3 * idx[k] + 1] + 1.f) * .5f;
    float u2 = (pts[3 * idx[k] + 2] + 1.f) * .5f;
    ua[k][0] = u0; ub[k][0] = u1;
    ua[k][1] = u0; ub[k][1] = u2;
    ua[k][2] = u1; ub[k][2] = u2;
  }

  uint2 g[2][2][3][2];       // [pt][lvl][plane][row]
  float rx[2][2][3], ry[2][2][3];
#pragma unroll
  for (int k = 0; k < 2; ++k)
#pragma unroll
    for (int l = 0; l < 2; ++l) {
      const float sc = lc.scale[10 + l];
      const unsigned st = lc.stride[10 + l], o = lc.offset[10 + l];
#pragma unroll
      for (int p = 0; p < 3; ++p) {
        float px = ua[k][p] * sc + .5f, py = ub[k][p] * sc + .5f;
        float fx = floorf(px), fy = floorf(py);
        rx[k][l][p] = px - fx; ry[k][l][p] = py - fy;
        unsigned i00 = (unsigned)fx + (unsigned)fy * st + o;
        const unsigned* tp = tab + (size_t)p * total;
        g[k][l][p][0] = *reinterpret_cast<const uint2*>(tp + i00);
        g[k][l][p][1] = *reinterpret_cast<const uint2*>(tp + i00 + st);
      }
    }

#pragma unroll
  for (int k = 0; k < 2; ++k)
#pragma unroll
    for (int l = 0; l < 2; ++l) {
      float s0 = 0.f, s1 = 0.f;
#pragma unroll
      for (int p = 0; p < 3; ++p) {
        float x = rx[k][l][p], y = ry[k][l][p];
        float w00 = (1.f - x) * (1.f - y), w10 = x * (1.f - y);
        float w01 = (1.f - x) * y,          w11 = x * y;
        float2 f00 = h2f(g[k][l][p][0].x), f10 = h2f(g[k][l][p][0].y);
        float2 f01 = h2f(g[k][l][p][1].x), f11 = h2f(g[k][l][p][1].y);
        s0 += w00 * f00.x + w10 * f10.x + w01 * f01.x + w11 * f11.x;
        s1 += w00 * f00.y + w10 * f10.y + w01 * f01.y + w11 * f11.y;
      }
      unsigned hv = __builtin_bit_cast(unsigned, __floats2half2_rn(s0, s1));
      unsigned* sl = l ? s11 : s10;
      __builtin_nontemporal_store(hv, sl + idx[k]);
    }
}

// ---- one hash level, all 3 planes, 2 pts/thread, 24 gathers in flight ----
__global__ __launch_bounds__(256) void k_hash_lvl(
    const float* __restrict__ pts, const unsigned* __restrict__ tab,
    unsigned* __restrict__ slice, float sc, unsigned o, unsigned total, int half)
{
  int t = blockIdx.x * 256 + threadIdx.x;
  if (t >= half) return;
  const int idx[2] = {t, t + half};

  float ua[2][3], ub[2][3];
#pragma unroll
  for (int k = 0; k < 2; ++k) {
    float u0 = (pts[3 * idx[k] + 0] + 1.f) * .5f;
    float u1 = (pts[3 * idx[k] + 1] + 1.f) * .5f;
    float u2 = (pts[3 * idx[k] + 2] + 1.f) * .5f;
    ua[k][0] = u0; ub[k][0] = u1;
    ua[k][1] = u0; ub[k][1] = u2;
    ua[k][2] = u1; ub[k][2] = u2;
  }

  unsigned g[2][3][4];
  float rx[2][3], ry[2][3];
#pragma unroll
  for (int k = 0; k < 2; ++k)
#pragma unroll
    for (int p = 0; p < 3; ++p) {
      float px = ua[k][p] * sc + .5f, py = ub[k][p] * sc + .5f;
      float fx = floorf(px), fy = floorf(py);
      rx[k][p] = px - fx; ry[k][p] = py - fy;
      unsigned x0 = (unsigned)fx, y0 = (unsigned)fy;
      unsigned hy0 = y0 * HASH_PRIME, hy1 = hy0 + HASH_PRIME;
      const unsigned* tp = tab + (size_t)p * total + o;
      g[k][p][0] = tp[(x0 ^ hy0) & HMASK];
      g[k][p][1] = tp[((x0 + 1u) ^ hy0) & HMASK];
      g[k][p][2] = tp[(x0 ^ hy1) & HMASK];
      g[k][p][3] = tp[((x0 + 1u) ^ hy1) & HMASK];
    }

#pragma unroll
  for (int k = 0; k < 2; ++k) {
    float s0 = 0.f, s1 = 0.f;
#pragma unroll
    for (int p = 0; p < 3; ++p) {
      float x = rx[k][p], y = ry[k][p];
      float w00 = (1.f - x) * (1.f - y), w10 = x * (1.f - y);
      float w01 = (1.f - x) * y,          w11 = x * y;
      float2 f00 = h2f(g[k][p][0]), f10 = h2f(g[k][p][1]);
      float2 f01 = h2f(g[k][p][2]), f11 = h2f(g[k][p][3]);
      s0 += w00 * f00.x + w10 * f10.x + w01 * f01.x + w11 * f11.x;
      s1 += w00 * f00.y + w10 * f10.y + w01 * f01.y + w11 * f11.y;
    }
    __builtin_nontemporal_store(
        __builtin_bit_cast(unsigned, __floats2half2_rn(s0, s1)), slice + idx[k]);
  }
}

// ---- final: levels 0-5 via LDS (3 plane phases) + levels 6-9 global +
//      slice merge (levels 10-15); single full-line writer of out ----
__global__ __launch_bounds__(256) void k_final(
    const float* __restrict__ pts, const unsigned* __restrict__ tab,
    const unsigned* __restrict__ slices,   // 6 x n, levels 10..15
    float* __restrict__ out, LvlC lc, unsigned total, int n)
{
  __shared__ unsigned lds[LDS_WORDS];
  int i = blockIdx.x * 256 + threadIdx.x;   // n % 256 == 0 (host-guarded)

  float u0 = (pts[3 * i + 0] + 1.f) * .5f;
  float u1 = (pts[3 * i + 1] + 1.f) * .5f;
  float u2 = (pts[3 * i + 2] + 1.f) * .5f;
  const float ua[3] = {u0, u0, u1}, ub[3] = {u1, u2, u2};

  float res[12];
#pragma unroll
  for (int j = 0; j < 12; ++j) res[j] = 0.f;

  // --- levels 0-5: stage one plane's tables into LDS, compute, repeat ---
  for (int p = 0; p < 3; ++p) {
    if (p) __syncthreads();                 // protect prior phase's readers
    const u4* src = reinterpret_cast<const u4*>(tab + (size_t)p * total);
    for (unsigned e = threadIdx.x; e < LDS_WORDS / 4; e += 256)
      reinterpret_cast<u4*>(lds)[e] = src[e];
    __syncthreads();
#pragma unroll
    for (int l = 0; l < 6; ++l) {
      float px = ua[p] * lc.scale[l] + .5f, py = ub[p] * lc.scale[l] + .5f;
      float fx = floorf(px), fy = floorf(py);
      float x = px - fx, y = py - fy;
      unsigned st = lc.stride[l];
      unsigned i00 = (unsigned)fx + (unsigned)fy * st + lc.offset[l];
      float2 f00 = h2f(lds[i00]),      f10 = h2f(lds[i00 + 1]);
      float2 f01 = h2f(lds[i00 + st]), f11 = h2f(lds[i00 + st + 1]);
      float w00 = (1.f - x) * (1.f - y), w10 = x * (1.f - y);
      float w01 = (1.f - x) * y,          w11 = x * y;
      res[2 * l + 0] += w00 * f00.x + w10 * f10.x + w01 * f01.x + w11 * f11.x;
      res[2 * l + 1] += w00 * f00.y + w10 * f10.y + w01 * f01.y + w11 * f11.y;
    }
  }

  // --- levels 6-9: 24 global gathers, all issued before any consume ---
  uint2 g[4][3][2];
  float gx[4][3], gy[4][3];
#pragma unroll
  for (int l = 0; l < 4; ++l) {
    const float sc = lc.scale[6 + l];
    const unsigned st = lc.stride[6 + l], o = lc.offset[6 + l];
#pragma unroll
    for (int p = 0; p < 3; ++p) {
      float px = ua[p] * sc + .5f, py = ub[p] * sc + .5f;
      float fx = floorf(px), fy = floorf(py);
      gx[l][p] = px - fx; gy[l][p] = py - fy;
      unsigned i00 = (unsigned)fx + (unsigned)fy * st + o;
      const unsigned* tp = tab + (size_t)p * total;
      g[l][p][0] = *reinterpret_cast<const uint2*>(tp + i00);
      g[l][p][1] = *reinterpret_cast<const uint2*>(tp + i00 + st);
    }
  }
  unsigned sl[6];
#pragma unroll
  for (int j = 0; j < 6; ++j) sl[j] = slices[(size_t)j * n + i];

  float res69[8];
#pragma unroll
  for (int l = 0; l < 4; ++l) {
    float s0 = 0.f, s1 = 0.f;
#pragma unroll
    for (int p = 0; p < 3; ++p) {
      float x = gx[l][p], y = gy[l][p];
      float w00 = (1.f - x) * (1.f - y), w10 = x * (1.f - y);
      float w01 = (1.f - x) * y,          w11 = x * y;
      float2 f00 = h2f(g[l][p][0].x), f10 = h2f(g[l][p][0].y);
      float2 f01 = h2f(g[l][p][1].x), f11 = h2f(g[l][p][1].y);
      s0 += w00 * f00.x + w10 * f10.x + w01 * f01.x + w11 * f11.x;
      s1 += w00 * f00.y + w10 * f10.y + w01 * f01.y + w11 * f11.y;
    }
    res69[2 * l] = s0; res69[2 * l + 1] = s1;
  }

  float v[32];
#pragma unroll
  for (int j = 0; j < 12; ++j) v[j] = res[j];
#pragma unroll
  for (int j = 0; j < 8; ++j) v[12 + j] = res69[j];
#pragma unroll
  for (int j = 0; j < 6; ++j) {
    float2 f = h2f(sl[j]);
    v[20 + 2 * j] = f.x; v[20 + 2 * j + 1] = f.y;
  }
  float* orow = out + (size_t)i * 32;
#pragma unroll
  for (int j = 0; j < 8; ++j)
    nt_store4(orow + 4 * j, v[4 * j], v[4 * j + 1], v[4 * j + 2], v[4 * j + 3]);
}

// ---- fallback: monolithic fp32 (guards failed) ----
__global__ __launch_bounds__(256) void k_fallback(
    const float* __restrict__ pts, const float2* __restrict__ txy,
    const float2* __restrict__ txz, const float2* __restrict__ tyz,
    float* __restrict__ out, LvlC lc, int n)
{
  int i = blockIdx.x * 256 + threadIdx.x;
  if (i >= n) return;
  float u0 = (pts[3 * i + 0] + 1.f) * .5f;
  float u1 = (pts[3 * i + 1] + 1.f) * .5f;
  float u2 = (pts[3 * i + 2] + 1.f) * .5f;
  const float ua[3] = {u0, u0, u1}, ub[3] = {u1, u2, u2};
  const float2* tabs[3] = {txy, txz, tyz};
  float acc[32];
#pragma unroll
  for (int j = 0; j < 32; ++j) acc[j] = 0.f;
#pragma unroll
  for (int l = 0; l < NLEV; ++l) {
    const float sc = lc.scale[l];
    const unsigned o = lc.offset[l], s = lc.stride[l];
#pragma unroll
    for (int p = 0; p < 3; ++p) {
      const float2* t = tabs[p];
      float px = ua[p] * sc + .5f, py = ub[p] * sc + .5f;
      float fx = floorf(px), fy = floorf(py);
      float rx = px - fx, ry = py - fy;
      unsigned x0 = (unsigned)fx, y0 = (unsigned)fy;
      float w00 = (1.f - rx) * (1.f - ry), w10 = rx * (1.f - ry);
      float w01 = (1.f - rx) * ry,          w11 = rx * ry;
      float2 f00, f10, f01, f11;
      if (l >= HASH_START) {
        unsigned hy0 = y0 * HASH_PRIME, hy1 = hy0 + HASH_PRIME;
        f00 = t[o + ((x0 ^ hy0) & HMASK)];
        f10 = t[o + (((x0 + 1u) ^ hy0) & HMASK)];
        f01 = t[o + ((x0 ^ hy1) & HMASK)];
        f11 = t[o + (((x0 + 1u) ^ hy1) & HMASK)];
      } else {
        unsigned i00 = x0 + y0 * s;
        float4 r0 = *reinterpret_cast<const float4*>(t + o + i00);
        float4 r1 = *reinterpret_cast<const float4*>(t + o + i00 + s);
        f00 = make_float2(r0.x, r0.y); f10 = make_float2(r0.z, r0.w);
        f01 = make_float2(r1.x, r1.y); f11 = make_float2(r1.z, r1.w);
      }
      acc[2 * l + 0] += w00 * f00.x + w10 * f10.x + w01 * f01.x + w11 * f11.x;
      acc[2 * l + 1] += w00 * f00.y + w10 * f10.y + w01 * f01.y + w11 * f11.y;
    }
  }
  float* orow = out + (size_t)i * 32;
#pragma unroll
  for (int j = 0; j < 8; ++j)
    nt_store4(orow + 4 * j, acc[4 * j], acc[4 * j + 1], acc[4 * j + 2], acc[4 * j + 3]);
}

static unsigned compute_levels(LvlC* lc)
{
  const double pls = std::pow(2.0, std::log2(2048.0 / 16.0) / 15.0);
  unsigned long long off = 0;
  for (int l = 0; l < NLEV; ++l) {
    double s = 16.0 * std::pow(pls, (double)l) - 1.0;
    lc->scale[l] = (float)s;
    long long r = (long long)std::ceil(s) + 1;
    long long dense = (r + 1) * (r + 1);
    long long sz = dense < (1LL << 19) ? dense : (1LL << 19);
    sz = ((sz + 7) / 8) * 8;
    lc->stride[l] = (unsigned)(r + 1);
    lc->offset[l] = (unsigned)off;
    off += (unsigned long long)sz;
  }
  return (unsigned)off;
}

extern "C" void kernel_launch(void* const* d_in, const int* in_sizes, int n_in,
                              void* d_out, int out_size, void* d_ws, size_t ws_size,
                              hipStream_t stream) {
  const float*  pts = (const float*)d_in[0];
  const float2* txy = (const float2*)d_in[1];
  const float2* txz = (const float2*)d_in[2];
  const float2* tyz = (const float2*)d_in[3];
  float* out = (float*)d_out;
  int n = in_sizes[0] / 3;  // 1048576 points

  LvlC lc;
  unsigned total = compute_levels(&lc);

  size_t tab_bytes = (size_t)3 * total * 4;
  size_t tab_al = (tab_bytes + 255) & ~(size_t)255;
  size_t need = tab_al + (size_t)6 * n * 4;

  bool ok = (n % 512 == 0) && (lc.offset[6] == LDS_WORDS) && (ws_size >= need);
  for (int l = HASH_START; l < NLEV; ++l) {
    unsigned sz = ((l + 1 < NLEV) ? lc.offset[l + 1] : total) - lc.offset[l];
    ok = ok && (sz == (1u << 19));
  }

  int block = 256;
  int grid = (n + block - 1) / block;
  if (!ok) {
    k_fallback<<<grid, block, 0, stream>>>(pts, txy, txz, tyz, out, lc, n);
    return;
  }

  unsigned* tab16 = (unsigned*)d_ws;
  unsigned* slices = (unsigned*)((char*)d_ws + tab_al);  // 6 arrays of n (levels 10..15)

  int half = n / 2;
  int gridh = half / block;

  k_convert<<<2048, 256, 0, stream>>>(txy, txz, tyz, tab16, total);
  k_dense1011<<<gridh, block, 0, stream>>>(pts, tab16, slices, slices + (size_t)n,
                                           lc, total, half);
  for (int l = HASH_START; l < NLEV; ++l)
    k_hash_lvl<<<gridh, block, 0, stream>>>(pts, tab16, slices + (size_t)(l - 10) * n,
                                            lc.scale[l], lc.offset[l], total, half);
  k_final<<<grid, block, 0, stream>>>(pts, tab16, slices, out, lc, total, n);
}